// Round 5
// baseline (125.044 us; speedup 1.0000x reference)
//
#include <hip/hip_runtime.h>
#include <math.h>

// Problem constants (from the JAX reference)
#define IMG    14
#define HW     196       // 14*14 spatial positions
#define DEPTH  512       // channels C
#define NB     512       // batch
#define HALF   98        // spatial positions per thread (196 / 2)

typedef float f32x4 __attribute__((ext_vector_type(4)));

// One wave per block. Lane = (h = lane>>5: spatial half, c5 = lane&31: f32x4
// channel group). Wave covers 128 channels x full spatial map. Each thread
// scans its 98 positions with dwordx4 loads (thread-local argmax, no LDS,
// no barrier); the two halves merge with one shfl_xor(32). Phase 2 re-reads
// (L3-hot), masks, stores. Grid: 512 b x 4 ctiles = 2048 one-wave blocks.
__global__ __launch_bounds__(64) void mask_kernel(const float* __restrict__ x,
                                                  float* __restrict__ out) {
    const int lane = threadIdx.x;         // 0..63
    const int h    = lane >> 5;           // spatial half, 0 or 1
    const int c5   = lane & 31;           // f32x4 group within 128-ch tile
    const int b    = blockIdx.x >> 2;
    const int ct   = blockIdx.x & 3;
    const int c0   = ct * 128 + (c5 << 2);
    const int s0   = h * HALF;

    const size_t base = ((size_t)b * HW + (size_t)s0) * DEPTH + (size_t)c0;
    const float* px = x + base;
    float*       po = out + base;

    // ---- Phase 1: thread-local streaming argmax over 98 positions ----
    float b0 = -INFINITY, b1 = -INFINITY, b2 = -INFINITY, b3 = -INFINITY;
    int   i0 = s0, i1 = s0, i2 = s0, i3 = s0;
#pragma unroll
    for (int k = 0; k < HALF; ++k) {
        const f32x4 v = *(const f32x4*)(px + (size_t)k * DEPTH);
        const int s = s0 + k;
        if (v.x > b0) { b0 = v.x; i0 = s; }
        if (v.y > b1) { b1 = v.y; i1 = s; }
        if (v.z > b2) { b2 = v.z; i2 = s; }
        if (v.w > b3) { b3 = v.w; i3 = s; }
    }

    // ---- Merge halves: lane h<->h^1 partner is lane^32 (same wave) ----
    // ascending-half order + strict > on the later half keeps first occurrence
    const float o0 = __shfl_xor(b0, 32); const int oi0 = __shfl_xor(i0, 32);
    const float o1 = __shfl_xor(b1, 32); const int oi1 = __shfl_xor(i1, 32);
    const float o2 = __shfl_xor(b2, 32); const int oi2 = __shfl_xor(i2, 32);
    const float o3 = __shfl_xor(b3, 32); const int oi3 = __shfl_xor(i3, 32);

    // lo = half-0 candidate, hi = half-1 candidate (branchless by h)
    float lv0 = (h == 0) ? b0 : o0, hv0 = (h == 0) ? o0 : b0;
    int   li0 = (h == 0) ? i0 : oi0, hi0 = (h == 0) ? oi0 : i0;
    float lv1 = (h == 0) ? b1 : o1, hv1 = (h == 0) ? o1 : b1;
    int   li1 = (h == 0) ? i1 : oi1, hi1 = (h == 0) ? oi1 : i1;
    float lv2 = (h == 0) ? b2 : o2, hv2 = (h == 0) ? o2 : b2;
    int   li2 = (h == 0) ? i2 : oi2, hi2 = (h == 0) ? oi2 : i2;
    float lv3 = (h == 0) ? b3 : o3, hv3 = (h == 0) ? o3 : b3;
    int   li3 = (h == 0) ? i3 : oi3, hi3 = (h == 0) ? oi3 : i3;

    const int mi0 = (hv0 > lv0) ? hi0 : li0;
    const int mi1 = (hv1 > lv1) ? hi1 : li1;
    const int mi2 = (hv2 > lv2) ? hi2 : li2;
    const int mi3 = (hv3 > lv3) ? hi3 : li3;

    const float fi0 = (float)(mi0 / IMG), fj0 = (float)(mi0 % IMG);
    const float fi1 = (float)(mi1 / IMG), fj1 = (float)(mi1 % IMG);
    const float fi2 = (float)(mi2 / IMG), fj2 = (float)(mi2 % IMG);
    const float fi3 = (float)(mi3 / IMG), fj3 = (float)(mi3 % IMG);
    const float TAU = (float)(0.5 / 196.0);

    // ---- Phase 2: re-read (L3-hot), mask, store; free-running pipeline ----
    int si = s0 / IMG;   // h==0 -> 0, h==1 -> 7
    int sj = 0;          // 98 = 7*14 exactly, so sj starts at 0 for both halves
#pragma unroll
    for (int k = 0; k < HALF; ++k) {
        const f32x4 v = *(const f32x4*)(px + (size_t)k * DEPTH);
        const float fsi = (float)si;
        const float fsj = (float)sj;
        f32x4 o;
        {
            const float dist = fabsf(fsi - fi0) + fabsf(fsj - fj0);
            o.x = v.x * (TAU * fmaxf(1.0f - (4.0f * dist) / 14.0f, -1.0f));
        }
        {
            const float dist = fabsf(fsi - fi1) + fabsf(fsj - fj1);
            o.y = v.y * (TAU * fmaxf(1.0f - (4.0f * dist) / 14.0f, -1.0f));
        }
        {
            const float dist = fabsf(fsi - fi2) + fabsf(fsj - fj2);
            o.z = v.z * (TAU * fmaxf(1.0f - (4.0f * dist) / 14.0f, -1.0f));
        }
        {
            const float dist = fabsf(fsi - fi3) + fabsf(fsj - fj3);
            o.w = v.w * (TAU * fmaxf(1.0f - (4.0f * dist) / 14.0f, -1.0f));
        }
        *(f32x4*)(po + (size_t)k * DEPTH) = o;
        ++sj;
        if (sj == IMG) { sj = 0; ++si; }
    }
}

extern "C" void kernel_launch(void* const* d_in, const int* in_sizes, int n_in,
                              void* d_out, int out_size, void* d_ws, size_t ws_size,
                              hipStream_t stream) {
    (void)in_sizes; (void)n_in; (void)out_size; (void)d_ws; (void)ws_size;
    const float* x = (const float*)d_in[0];
    float* out = (float*)d_out;
    dim3 grid(NB * 4);   // 2048 one-wave blocks
    dim3 block(64);
    hipLaunchKernelGGL(mask_kernel, grid, block, 0, stream, x, out);
}

// Round 6
// 89.988 us; speedup vs baseline: 1.3896x; 1.3896x over previous
//
#include <hip/hip_runtime.h>
#include <math.h>

// Problem constants (from the JAX reference)
#define IMG    14
#define HW     196       // 14*14 spatial positions
#define DEPTH  512       // channels C
#define NB     512       // batch
#define RPT    7         // spatial rows per thread (196 / 28)
#define GPR    16        // f32x4 channel groups per block tile
#define CTILE  64        // channels per block
#define NWAVE  7
#define BLK    448

typedef float f32x4 __attribute__((ext_vector_type(4)));
typedef int   i32x4 __attribute__((ext_vector_type(4)));

// Block: 448 threads = 7 waves. Thread (g = tid&15, q = tid>>4): one f32x4
// channel group x 7 consecutive spatial positions. Values are staged in a
// thread-PRIVATE LDS slab (compiler-proof: cannot be rematerialized as global
// re-loads like the register versions were). Argmax reduction: shfl_xor
// butterfly over the 4 q's per wave + tiny LDS partial array across waves.
// Grid: 512 b x 8 ctiles = 4096 blocks; LDS 53.8 KB -> 3 blocks/CU (21 waves).
__global__ __launch_bounds__(BLK) void mask_kernel(const float* __restrict__ x,
                                                   float* __restrict__ out) {
    const int tid = threadIdx.x;
    const int g   = tid & 15;      // channel group
    const int q   = tid >> 4;      // spatial segment 0..27
    const int w   = tid >> 6;      // wave 0..6
    const int b   = blockIdx.x >> 3;
    const int ct  = blockIdx.x & 7;
    const int c0  = ct * CTILE + (g << 2);

    __shared__ f32x4 tile[BLK * RPT];    // 50176 B: per-thread value store
    __shared__ f32x4 pmax[NWAVE][GPR];   // 1792 B: per-wave argmax partial (val)
    __shared__ i32x4 pidx[NWAVE][GPR];   // 1792 B: per-wave argmax partial (idx)

    // Launder the tile pointer: makes provenance opaque so LLVM cannot
    // store-forward the LDS writes (which would revive the global-remat
    // pathology seen in rounds 1/3/4).
    f32x4* tl = tile;
    {
        unsigned long long p = (unsigned long long)tl;
        asm volatile("" : "+v"(p));
        tl = (f32x4*)p;
    }
    f32x4* my = tl + tid * RPT;

    const size_t base = ((size_t)b * HW + (size_t)q * RPT) * DEPTH + (size_t)c0;
    const float* px = x + base;
    float*       po = out + base;

    // ---- Phase 1: load once, stash in LDS, streaming argmax ----
    float b0 = -INFINITY, b1 = -INFINITY, b2 = -INFINITY, b3 = -INFINITY;
    int   i0 = 0, i1 = 0, i2 = 0, i3 = 0;
#pragma unroll
    for (int k = 0; k < RPT; ++k) {
        const f32x4 v = *(const f32x4*)(px + (size_t)k * DEPTH);
        my[k] = v;
        const int s = q * RPT + k;
        if (v.x > b0) { b0 = v.x; i0 = s; }
        if (v.y > b1) { b1 = v.y; i1 = s; }
        if (v.z > b2) { b2 = v.z; i2 = s; }
        if (v.w > b3) { b3 = v.w; i3 = s; }
    }

    // ---- Intra-wave butterfly: lanes {l, l^16, l^32, l^48} share g ----
    // (val,idx) merge with smaller-idx tie-break == first occurrence, matching
    // jnp.argmax regardless of merge order.
#pragma unroll
    for (int m = 16; m <= 32; m <<= 1) {
        const float o0 = __shfl_xor(b0, m); const int oi0 = __shfl_xor(i0, m);
        const float o1 = __shfl_xor(b1, m); const int oi1 = __shfl_xor(i1, m);
        const float o2 = __shfl_xor(b2, m); const int oi2 = __shfl_xor(i2, m);
        const float o3 = __shfl_xor(b3, m); const int oi3 = __shfl_xor(i3, m);
        if (o0 > b0 || (o0 == b0 && oi0 < i0)) { b0 = o0; i0 = oi0; }
        if (o1 > b1 || (o1 == b1 && oi1 < i1)) { b1 = o1; i1 = oi1; }
        if (o2 > b2 || (o2 == b2 && oi2 < i2)) { b2 = o2; i2 = oi2; }
        if (o3 > b3 || (o3 == b3 && oi3 < i3)) { b3 = o3; i3 = oi3; }
    }

    if ((tid & 63) < 16) {
        pmax[w][g] = (f32x4){b0, b1, b2, b3};
        pidx[w][g] = (i32x4){i0, i1, i2, i3};
    }
    __syncthreads();

    // ---- Cross-wave merge (7 partials, broadcast reads) ----
    f32x4 mv = pmax[0][g];
    i32x4 mi = pidx[0][g];
#pragma unroll
    for (int r = 1; r < NWAVE; ++r) {
        const f32x4 vv = pmax[r][g];
        const i32x4 ii = pidx[r][g];
        if (vv.x > mv.x || (vv.x == mv.x && ii.x < mi.x)) { mv.x = vv.x; mi.x = ii.x; }
        if (vv.y > mv.y || (vv.y == mv.y && ii.y < mi.y)) { mv.y = vv.y; mi.y = ii.y; }
        if (vv.z > mv.z || (vv.z == mv.z && ii.z < mi.z)) { mv.z = vv.z; mi.z = ii.z; }
        if (vv.w > mv.w || (vv.w == mv.w && ii.w < mi.w)) { mv.w = vv.w; mi.w = ii.w; }
    }

    const float fi0 = (float)(mi.x / IMG), fj0 = (float)(mi.x % IMG);
    const float fi1 = (float)(mi.y / IMG), fj1 = (float)(mi.y % IMG);
    const float fi2 = (float)(mi.z / IMG), fj2 = (float)(mi.z % IMG);
    const float fi3 = (float)(mi.w / IMG), fj3 = (float)(mi.w % IMG);
    const float TAU = (float)(0.5 / 196.0);

    // ---- Phase 2: read own rows back from LDS, mask, store ----
#pragma unroll
    for (int k = 0; k < RPT; ++k) {
        const f32x4 v = my[k];
        const int s = q * RPT + k;
        const float fsi = (float)(s / IMG);
        const float fsj = (float)(s % IMG);
        f32x4 o;
        {
            const float dist = fabsf(fsi - fi0) + fabsf(fsj - fj0);
            o.x = v.x * (TAU * fmaxf(1.0f - (4.0f * dist) / 14.0f, -1.0f));
        }
        {
            const float dist = fabsf(fsi - fi1) + fabsf(fsj - fj1);
            o.y = v.y * (TAU * fmaxf(1.0f - (4.0f * dist) / 14.0f, -1.0f));
        }
        {
            const float dist = fabsf(fsi - fi2) + fabsf(fsj - fj2);
            o.z = v.z * (TAU * fmaxf(1.0f - (4.0f * dist) / 14.0f, -1.0f));
        }
        {
            const float dist = fabsf(fsi - fi3) + fabsf(fsj - fj3);
            o.w = v.w * (TAU * fmaxf(1.0f - (4.0f * dist) / 14.0f, -1.0f));
        }
        *(f32x4*)(po + (size_t)k * DEPTH) = o;
    }
}

extern "C" void kernel_launch(void* const* d_in, const int* in_sizes, int n_in,
                              void* d_out, int out_size, void* d_ws, size_t ws_size,
                              hipStream_t stream) {
    (void)in_sizes; (void)n_in; (void)out_size; (void)d_ws; (void)ws_size;
    const float* x = (const float*)d_in[0];
    float* out = (float*)d_out;
    dim3 grid(NB * (DEPTH / CTILE));  // 4096
    dim3 block(BLK);
    hipLaunchKernelGGL(mask_kernel, grid, block, 0, stream, x, out);
}